// Round 10
// baseline (135.647 us; speedup 1.0000x reference)
//
#include <hip/hip_runtime.h>
#include <math.h>

// Bilateral filter, 5x5, reflect pad, sigma_spatial=2.0, sigma_range=0.1
// image: (16, 3, 512, 512) fp32 -> out same shape fp32.
//
// R10: 4x4 output tile per thread + symmetric-pair sharing.
// w(p,q) is symmetric in (p,q), so each pair internal to the tile is
// computed ONCE and accumulated into both endpoints:
//   90 internal pairs  x {sub,fma,exp2,fma,add,fma,add} (20 cyc)
//  204 boundary taps   x {sub,fma,exp2,fma,add}         (16 cyc)
// vs 384 directed taps x 16 cyc without sharing. exp2 count 294 vs 384.
// Issue model (established R1..R9): scalar f32 = 2 cyc/wave64, VOP3P pk = 4
// (no win), v_exp_f32 ~ 8, TRANS shares the issue port; LDS gathers with
// data-dependent indices bank-conflict (R9) -> pure register kernel.
// Window prescaled by S = sqrt(50*log2e) so t = fma(d,d,q) is the exp2 arg.

#define IMG_H 512
#define IMG_W 512

#define S_PRE 8.4932180028801907f    // sqrt(50 * log2(e))
#define QC    0.18033688011112042f   // 0.125 * log2(e)

__device__ __forceinline__ float frcp(float x) {
    return __builtin_amdgcn_rcpf(x);
}

// Each thread computes a 4x4 pixel tile of one (b,c) plane.
// tid bits: [6:0] = x-group (128 groups of 4 cols) -> y uniform per wave,
//           [13:7] = y-group (128 groups of 4 rows), [..:14] = plane (48).
__global__ __launch_bounds__(256, 4) void bilateral5x5_kernel(
        const float* __restrict__ img, float* __restrict__ out) {
    const int tid = blockIdx.x * 256 + threadIdx.x;
    const int xg = tid & 127;
    const int yg = (tid >> 7) & 127;
    const int p  = tid >> 14;

    const float* __restrict__ plane = img + (size_t)p * (IMG_H * IMG_W);
    float* __restrict__ oplane      = out + (size_t)p * (IMG_H * IMG_W);
    const int x0 = xg << 2;
    const int y0 = yg << 2;

    // x-border (PAD=2): reflected cols land inside the central float4 ->
    // clamped in-bounds (8B-aligned) loads + selects, no divergence.
    const bool xlo = (xg == 0);
    const bool xhi = (xg == 127);
    const int lox = xlo ? x0 : (x0 - 2);
    const int hix = xhi ? (x0 + 2) : (x0 + 4);

    // 8x8 window (rows y0-2..y0+5, cols x0-2..x0+5), prescaled by S_PRE
    float W[8][8];
#pragma unroll
    for (int r = 0; r < 8; ++r) {
        int yy = y0 + r - 2;
        yy = (yy < 0) ? -yy : yy;                 // reflect top
        yy = (yy > 511) ? (1022 - yy) : yy;       // reflect bottom
        const float* __restrict__ row = plane + (size_t)yy * IMG_W;
        const float2 lo = *reinterpret_cast<const float2*>(row + lox);
        const float4 md = *reinterpret_cast<const float4*>(row + x0);
        const float2 hi = *reinterpret_cast<const float2*>(row + hix);
        W[r][0] = (xlo ? md.z : lo.x) * S_PRE;   // col -2 -> reflect col 2
        W[r][1] = (xlo ? md.y : lo.y) * S_PRE;   // col -1 -> reflect col 1
        W[r][2] = md.x * S_PRE;
        W[r][3] = md.y * S_PRE;
        W[r][4] = md.z * S_PRE;
        W[r][5] = md.w * S_PRE;
        W[r][6] = (xhi ? md.z : hi.x) * S_PRE;   // col 512 -> col 510
        W[r][7] = (xhi ? md.y : hi.y) * S_PRE;   // col 513 -> col 509
    }

    // center tap: w = 1 exactly; acc holds S * sum(w*n)
    float acc[4][4], nrm[4][4];
#pragma unroll
    for (int r = 0; r < 4; ++r)
#pragma unroll
        for (int c = 0; c < 4; ++c) {
            acc[r][c] = W[r + 2][c + 2];
            nrm[r][c] = 1.0f;
        }

    // ---- shared internal pairs (both endpoints are output pixels) ----
    // canonical offsets: dy>0, or dy==0 && dx>0
#pragma unroll
    for (int dy = 0; dy <= 2; ++dy) {
#pragma unroll
        for (int dx = -2; dx <= 2; ++dx) {
            if (dy == 0 && dx <= 0) continue;
            const float q = (float)(dy * dy + dx * dx) * QC;
#pragma unroll
            for (int r = 2; r <= 5; ++r) {
#pragma unroll
                for (int c = 2; c <= 5; ++c) {
                    const int r2 = r + dy, c2 = c + dx;
                    if (r2 < 2 || r2 > 5 || c2 < 2 || c2 > 5) continue;
                    const float d = W[r2][c2] - W[r][c];
                    const float t = fmaf(d, d, q);
                    const float e = __builtin_amdgcn_exp2f(-t);
                    acc[r - 2][c - 2]   = fmaf(e, W[r2][c2], acc[r - 2][c - 2]);
                    nrm[r - 2][c - 2]  += e;
                    acc[r2 - 2][c2 - 2] = fmaf(e, W[r][c], acc[r2 - 2][c2 - 2]);
                    nrm[r2 - 2][c2 - 2] += e;
                }
            }
        }
    }

    // ---- boundary taps (partner in the halo) ----
#pragma unroll
    for (int dy = -2; dy <= 2; ++dy) {
#pragma unroll
        for (int dx = -2; dx <= 2; ++dx) {
            if (dy == 0 && dx == 0) continue;
            const float q = (float)(dy * dy + dx * dx) * QC;
#pragma unroll
            for (int r = 2; r <= 5; ++r) {
#pragma unroll
                for (int c = 2; c <= 5; ++c) {
                    const int r2 = r + dy, c2 = c + dx;
                    if (r2 >= 2 && r2 <= 5 && c2 >= 2 && c2 <= 5) continue;
                    const float d = W[r2][c2] - W[r][c];
                    const float t = fmaf(d, d, q);
                    const float e = __builtin_amdgcn_exp2f(-t);
                    acc[r - 2][c - 2]  = fmaf(e, W[r2][c2], acc[r - 2][c - 2]);
                    nrm[r - 2][c - 2] += e;
                }
            }
        }
    }

    // out = (acc/S) / (nrm + 1e-8) = acc * rcp(S*nrm + S*1e-8)
    const float Seps = S_PRE * 1e-8f;
#pragma unroll
    for (int r = 0; r < 4; ++r) {
        float4 o;
        o.x = acc[r][0] * frcp(fmaf(nrm[r][0], S_PRE, Seps));
        o.y = acc[r][1] * frcp(fmaf(nrm[r][1], S_PRE, Seps));
        o.z = acc[r][2] * frcp(fmaf(nrm[r][2], S_PRE, Seps));
        o.w = acc[r][3] * frcp(fmaf(nrm[r][3], S_PRE, Seps));
        *reinterpret_cast<float4*>(oplane + (size_t)(y0 + r) * IMG_W + x0) = o;
    }
}

extern "C" void kernel_launch(void* const* d_in, const int* in_sizes, int n_in,
                              void* d_out, int out_size, void* d_ws, size_t ws_size,
                              hipStream_t stream) {
    const float* img = (const float*)d_in[0];
    float* out = (float*)d_out;

    const int n = in_sizes[0];                 // 16*3*512*512 = 12,582,912
    const int threads = n / 16;                // 4x4 pixels per thread
    const int block = 256;
    const int grid = threads / block;          // 3072

    bilateral5x5_kernel<<<grid, block, 0, stream>>>(img, out);
}

// Round 11
// 53.417 us; speedup vs baseline: 2.5394x; 2.5394x over previous
//
#include <hip/hip_runtime.h>
#include <math.h>

// Bilateral filter, 5x5, reflect pad, sigma_spatial=2.0, sigma_range=0.1
// image: (16, 3, 512, 512) fp32 -> out same shape fp32.
//
// R11 = R10 without the __launch_bounds__(256,4) register cap.
// R10's 135us was pure scratch spill: (256,4) caps VGPR at 128 but the
// 4x4-tile state needs ~150 -> W[8][8] spilled (WRITE_SIZE 393MB, 8x ideal).
// Algorithm unchanged (absmax was identical to R4's):
//   4x4 output tile per thread; w(p,q) symmetric -> 90 internal pairs
//   computed once, accumulated into both endpoints (20 cyc each);
//   204 boundary taps (16 cyc each). Tap cost 5064 cyc/16px = 4.95 cyc/px
//   vs R4's 6.0, and window build (8 rows) amortized over 16 px vs 5/8.
// Issue model (R1..R9): scalar f32 = 2 cyc/wave64, v_exp_f32 ~ 8 cyc,
// VOP3P packed gives no win, LDS data-dependent gathers conflict.

#define IMG_H 512
#define IMG_W 512

#define S_PRE 8.4932180028801907f    // sqrt(50 * log2(e))
#define QC    0.18033688011112042f   // 0.125 * log2(e)

__device__ __forceinline__ float frcp(float x) {
    return __builtin_amdgcn_rcpf(x);
}

// Each thread computes a 4x4 pixel tile of one (b,c) plane.
// tid bits: [6:0] = x-group (128 groups of 4 cols) -> y uniform per wave,
//           [13:7] = y-group (128 groups of 4 rows), [..:14] = plane (48).
__global__ __launch_bounds__(256) void bilateral5x5_kernel(
        const float* __restrict__ img, float* __restrict__ out) {
    const int tid = blockIdx.x * 256 + threadIdx.x;
    const int xg = tid & 127;
    const int yg = (tid >> 7) & 127;
    const int p  = tid >> 14;

    const float* __restrict__ plane = img + (size_t)p * (IMG_H * IMG_W);
    float* __restrict__ oplane      = out + (size_t)p * (IMG_H * IMG_W);
    const int x0 = xg << 2;
    const int y0 = yg << 2;

    // x-border (PAD=2): reflected cols land inside the central float4 ->
    // clamped in-bounds (8B-aligned) loads + selects, no divergence.
    const bool xlo = (xg == 0);
    const bool xhi = (xg == 127);
    const int lox = xlo ? x0 : (x0 - 2);
    const int hix = xhi ? (x0 + 2) : (x0 + 4);

    // 8x8 window (rows y0-2..y0+5, cols x0-2..x0+5), prescaled by S_PRE
    float W[8][8];
#pragma unroll
    for (int r = 0; r < 8; ++r) {
        int yy = y0 + r - 2;
        yy = (yy < 0) ? -yy : yy;                 // reflect top
        yy = (yy > 511) ? (1022 - yy) : yy;       // reflect bottom
        const float* __restrict__ row = plane + (size_t)yy * IMG_W;
        const float2 lo = *reinterpret_cast<const float2*>(row + lox);
        const float4 md = *reinterpret_cast<const float4*>(row + x0);
        const float2 hi = *reinterpret_cast<const float2*>(row + hix);
        W[r][0] = (xlo ? md.z : lo.x) * S_PRE;   // col -2 -> reflect col 2
        W[r][1] = (xlo ? md.y : lo.y) * S_PRE;   // col -1 -> reflect col 1
        W[r][2] = md.x * S_PRE;
        W[r][3] = md.y * S_PRE;
        W[r][4] = md.z * S_PRE;
        W[r][5] = md.w * S_PRE;
        W[r][6] = (xhi ? md.z : hi.x) * S_PRE;   // col 512 -> col 510
        W[r][7] = (xhi ? md.y : hi.y) * S_PRE;   // col 513 -> col 509
    }

    // center tap: w = 1 exactly; acc holds S * sum(w*n)
    float acc[4][4], nrm[4][4];
#pragma unroll
    for (int r = 0; r < 4; ++r)
#pragma unroll
        for (int c = 0; c < 4; ++c) {
            acc[r][c] = W[r + 2][c + 2];
            nrm[r][c] = 1.0f;
        }

    // ---- shared internal pairs (both endpoints are output pixels) ----
    // canonical offsets: dy>0, or dy==0 && dx>0
#pragma unroll
    for (int dy = 0; dy <= 2; ++dy) {
#pragma unroll
        for (int dx = -2; dx <= 2; ++dx) {
            if (dy == 0 && dx <= 0) continue;
            const float q = (float)(dy * dy + dx * dx) * QC;
#pragma unroll
            for (int r = 2; r <= 5; ++r) {
#pragma unroll
                for (int c = 2; c <= 5; ++c) {
                    const int r2 = r + dy, c2 = c + dx;
                    if (r2 < 2 || r2 > 5 || c2 < 2 || c2 > 5) continue;
                    const float d = W[r2][c2] - W[r][c];
                    const float t = fmaf(d, d, q);
                    const float e = __builtin_amdgcn_exp2f(-t);
                    acc[r - 2][c - 2]   = fmaf(e, W[r2][c2], acc[r - 2][c - 2]);
                    nrm[r - 2][c - 2]  += e;
                    acc[r2 - 2][c2 - 2] = fmaf(e, W[r][c], acc[r2 - 2][c2 - 2]);
                    nrm[r2 - 2][c2 - 2] += e;
                }
            }
        }
    }

    // ---- boundary taps (partner in the halo) ----
#pragma unroll
    for (int dy = -2; dy <= 2; ++dy) {
#pragma unroll
        for (int dx = -2; dx <= 2; ++dx) {
            if (dy == 0 && dx == 0) continue;
            const float q = (float)(dy * dy + dx * dx) * QC;
#pragma unroll
            for (int r = 2; r <= 5; ++r) {
#pragma unroll
                for (int c = 2; c <= 5; ++c) {
                    const int r2 = r + dy, c2 = c + dx;
                    if (r2 >= 2 && r2 <= 5 && c2 >= 2 && c2 <= 5) continue;
                    const float d = W[r2][c2] - W[r][c];
                    const float t = fmaf(d, d, q);
                    const float e = __builtin_amdgcn_exp2f(-t);
                    acc[r - 2][c - 2]  = fmaf(e, W[r2][c2], acc[r - 2][c - 2]);
                    nrm[r - 2][c - 2] += e;
                }
            }
        }
    }

    // out = (acc/S) / (nrm + 1e-8) = acc * rcp(S*nrm + S*1e-8)
    const float Seps = S_PRE * 1e-8f;
#pragma unroll
    for (int r = 0; r < 4; ++r) {
        float4 o;
        o.x = acc[r][0] * frcp(fmaf(nrm[r][0], S_PRE, Seps));
        o.y = acc[r][1] * frcp(fmaf(nrm[r][1], S_PRE, Seps));
        o.z = acc[r][2] * frcp(fmaf(nrm[r][2], S_PRE, Seps));
        o.w = acc[r][3] * frcp(fmaf(nrm[r][3], S_PRE, Seps));
        *reinterpret_cast<float4*>(oplane + (size_t)(y0 + r) * IMG_W + x0) = o;
    }
}

extern "C" void kernel_launch(void* const* d_in, const int* in_sizes, int n_in,
                              void* d_out, int out_size, void* d_ws, size_t ws_size,
                              hipStream_t stream) {
    const float* img = (const float*)d_in[0];
    float* out = (float*)d_out;

    const int n = in_sizes[0];                 // 16*3*512*512 = 12,582,912
    const int threads = n / 16;                // 4x4 pixels per thread
    const int block = 256;
    const int grid = threads / block;          // 3072

    bilateral5x5_kernel<<<grid, block, 0, stream>>>(img, out);
}

// Round 12
// 49.358 us; speedup vs baseline: 2.7482x; 1.0822x over previous
//
#include <hip/hip_runtime.h>
#include <math.h>

// Bilateral filter, 5x5, reflect pad, sigma_spatial=2.0, sigma_range=0.1
// image: (16, 3, 512, 512) fp32 -> out same shape fp32.
//
// R12: streaming symmetric 4x4 tile. R11 proved the pair-shared algorithm
// (294 exps / 16 px vs 384) but died on register pressure (96-reg live
// window -> v_mov churn, 8775 cyc/wave vs 5470 modeled, occupancy 18%).
// Fix: stream window rows r=0..7; at step r only rows r-2..r live
// (W[3][8] = 24 regs). All symmetric pairs {(r-dy,cA),(r,cB)}, dy<=2,
// with >=1 output endpoint are consumed when row r arrives:
//   shared pair (both output): sub,fma,exp2, 2x(fma,add)  -> 6 VALU + 1 TRANS
//   boundary (one output):     sub,fma,exp2, fma,add      -> 4 VALU + 1 TRANS
// exp2 arg via t = fmaf(d, -d, -q) (neg = free src modifier).
// Verified pair count: 44 horiz + 118 dy=1 + 132 dy=2 = 294.
// Issue model (R1-R11): scalar VALU 2 cyc/wave64, v_exp ~9, shared port.

#define IMG_H 512
#define IMG_W 512

#define S_PRE 8.4932180028801907f    // sqrt(50 * log2(e))
#define QC    0.18033688011112042f   // 0.125 * log2(e)

__device__ __forceinline__ float frcp(float x) {
    return __builtin_amdgcn_rcpf(x);
}

// Each thread computes a 4x4 pixel tile of one (b,c) plane.
// tid bits: [6:0] = x-group (128 groups of 4 cols) -> y uniform per wave,
//           [13:7] = y-group (128 groups of 4 rows), [..:14] = plane (48).
__global__ __launch_bounds__(256) void bilateral5x5_kernel(
        const float* __restrict__ img, float* __restrict__ out) {
    const int tid = blockIdx.x * 256 + threadIdx.x;
    const int xg = tid & 127;
    const int yg = (tid >> 7) & 127;
    const int p  = tid >> 14;

    const float* __restrict__ plane = img + (size_t)p * (IMG_H * IMG_W);
    float* __restrict__ oplane      = out + (size_t)p * (IMG_H * IMG_W);
    const int x0 = xg << 2;
    const int y0 = yg << 2;

    // x-border (PAD=2): reflected cols land inside the central float4 ->
    // clamped in-bounds (8B-aligned) loads + selects, no divergence.
    const bool xlo = (xg == 0);
    const bool xhi = (xg == 127);
    const int lox = xlo ? x0 : (x0 - 2);
    const int hix = xhi ? (x0 + 2) : (x0 + 4);

    float W[3][8];          // rolling window rows (r-2, r-1, r) mod 3
    float acc[4][4], nrm[4][4];

#pragma unroll
    for (int r = 0; r < 8; ++r) {
        // ---- load window row r (y = y0 + r - 2, reflected), prescale ----
        {
            int yy = y0 + r - 2;
            yy = (yy < 0) ? -yy : yy;
            yy = (yy > 511) ? (1022 - yy) : yy;
            const float* __restrict__ row = plane + (size_t)yy * IMG_W;
            const float2 lo = *reinterpret_cast<const float2*>(row + lox);
            const float4 md = *reinterpret_cast<const float4*>(row + x0);
            const float2 hi = *reinterpret_cast<const float2*>(row + hix);
            float* Wr = W[r % 3];
            Wr[0] = (xlo ? md.z : lo.x) * S_PRE;
            Wr[1] = (xlo ? md.y : lo.y) * S_PRE;
            Wr[2] = md.x * S_PRE;
            Wr[3] = md.y * S_PRE;
            Wr[4] = md.z * S_PRE;
            Wr[5] = md.w * S_PRE;
            Wr[6] = (xhi ? md.z : hi.x) * S_PRE;
            Wr[7] = (xhi ? md.y : hi.y) * S_PRE;
        }

        const bool rOut = (r >= 2 && r <= 5);

        // ---- center tap init for output row r ----
        if (rOut) {
#pragma unroll
            for (int c = 0; c < 4; ++c) {
                acc[r - 2][c] = W[r % 3][c + 2];
                nrm[r - 2][c] = 1.0f;
            }
        }

        // ---- horizontal pairs within row r (only output rows) ----
        if (rOut) {
#pragma unroll
            for (int dx = 1; dx <= 2; ++dx) {
#pragma unroll
                for (int c = 0; c + dx < 8; ++c) {
                    const int cB = c + dx;
                    const bool Aout = (c >= 2 && c <= 5);
                    const bool Bout = (cB >= 2 && cB <= 5);
                    if (!Aout && !Bout) continue;
                    const float a = W[r % 3][c];
                    const float b = W[r % 3][cB];
                    const float nq = -(float)(dx * dx) * QC;
                    const float d = b - a;
                    const float e = __builtin_amdgcn_exp2f(fmaf(d, -d, nq));
                    if (Aout) {
                        acc[r - 2][c - 2]  = fmaf(e, b, acc[r - 2][c - 2]);
                        nrm[r - 2][c - 2] += e;
                    }
                    if (Bout) {
                        acc[r - 2][cB - 2]  = fmaf(e, a, acc[r - 2][cB - 2]);
                        nrm[r - 2][cB - 2] += e;
                    }
                }
            }
        }

        // ---- cross-row pairs (row r-dy, row r), dy in {1,2} ----
#pragma unroll
        for (int dy = 1; dy <= 2; ++dy) {
            if (r - dy < 0) continue;
            const int rA = r - dy;
            const bool AoutRow = (rA >= 2 && rA <= 5);
#pragma unroll
            for (int dx = -2; dx <= 2; ++dx) {
#pragma unroll
                for (int c = 0; c < 8; ++c) {
                    const int cB = c + dx;
                    if (cB < 0 || cB > 7) continue;
                    const bool Aout = AoutRow && (c >= 2 && c <= 5);
                    const bool Bout = rOut && (cB >= 2 && cB <= 5);
                    if (!Aout && !Bout) continue;
                    const float a = W[rA % 3][c];
                    const float b = W[r % 3][cB];
                    const float nq = -(float)(dy * dy + dx * dx) * QC;
                    const float d = b - a;
                    const float e = __builtin_amdgcn_exp2f(fmaf(d, -d, nq));
                    if (Aout) {
                        acc[rA - 2][c - 2]  = fmaf(e, b, acc[rA - 2][c - 2]);
                        nrm[rA - 2][c - 2] += e;
                    }
                    if (Bout) {
                        acc[r - 2][cB - 2]  = fmaf(e, a, acc[r - 2][cB - 2]);
                        nrm[r - 2][cB - 2] += e;
                    }
                }
            }
        }
    }

    // out = (acc/S) / (nrm + 1e-8) = acc * rcp(S*nrm + S*1e-8)
    const float Seps = S_PRE * 1e-8f;
#pragma unroll
    for (int r = 0; r < 4; ++r) {
        float4 o;
        o.x = acc[r][0] * frcp(fmaf(nrm[r][0], S_PRE, Seps));
        o.y = acc[r][1] * frcp(fmaf(nrm[r][1], S_PRE, Seps));
        o.z = acc[r][2] * frcp(fmaf(nrm[r][2], S_PRE, Seps));
        o.w = acc[r][3] * frcp(fmaf(nrm[r][3], S_PRE, Seps));
        *reinterpret_cast<float4*>(oplane + (size_t)(y0 + r) * IMG_W + x0) = o;
    }
}

extern "C" void kernel_launch(void* const* d_in, const int* in_sizes, int n_in,
                              void* d_out, int out_size, void* d_ws, size_t ws_size,
                              hipStream_t stream) {
    const float* img = (const float*)d_in[0];
    float* out = (float*)d_out;

    const int n = in_sizes[0];                 // 16*3*512*512 = 12,582,912
    const int threads = n / 16;                // 4x4 pixels per thread
    const int block = 256;
    const int grid = threads / block;          // 3072

    bilateral5x5_kernel<<<grid, block, 0, stream>>>(img, out);
}